// Round 4
// baseline (733.391 us; speedup 1.0000x reference)
//
#include <hip/hip_runtime.h>
#include <hip/hip_bf16.h>

#define Bb 8
#define Cc 256
#define Nn 4096
#define Dd 32

typedef short bf16x8 __attribute__((ext_vector_type(8)));
typedef short bf16x4 __attribute__((ext_vector_type(4)));
typedef float f32x4 __attribute__((ext_vector_type(4)));

__device__ __forceinline__ void glds16(const void* g, void* l) {
    __builtin_amdgcn_global_load_lds(
        (const __attribute__((address_space(1))) unsigned int*)g,
        (__attribute__((address_space(3))) unsigned int*)l, 16, 0, 0);
}

// ---------------- transpose-convert x -> x_t[b][n][c] bf16, fused stats ----------------
__global__ __launch_bounds__(256) void convt_kernel(
    const float* __restrict__ x, __hip_bfloat16* __restrict__ x_t,
    float* __restrict__ sum_ws, float* __restrict__ sumsq_ws)
{
    __shared__ __hip_bfloat16 tile[64][68];
    const int n0 = blockIdx.x * 64, c0 = blockIdx.y * 64, b = blockIdx.z;
    const int t = threadIdx.x;

#pragma unroll
    for (int i = 0; i < 4; i++) {
        int id = i * 256 + t;
        int row = id >> 4, col4 = id & 15;
        float4 v = *(const float4*)(x + ((size_t)(b * Cc + c0 + row)) * Nn + n0 + col4 * 4);
        bf16x4 bv;
        bv[0] = __bfloat16_as_short(__float2bfloat16(v.x));
        bv[1] = __bfloat16_as_short(__float2bfloat16(v.y));
        bv[2] = __bfloat16_as_short(__float2bfloat16(v.z));
        bv[3] = __bfloat16_as_short(__float2bfloat16(v.w));
        *(bf16x4*)((void*)&tile[row][col4 * 4]) = bv;
        float ls  = v.x + v.y + v.z + v.w;
        float ls2 = v.x * v.x + v.y * v.y + v.z * v.z + v.w * v.w;
        ls  += __shfl_xor(ls, 1, 16);  ls2 += __shfl_xor(ls2, 1, 16);
        ls  += __shfl_xor(ls, 2, 16);  ls2 += __shfl_xor(ls2, 2, 16);
        ls  += __shfl_xor(ls, 4, 16);  ls2 += __shfl_xor(ls2, 4, 16);
        ls  += __shfl_xor(ls, 8, 16);  ls2 += __shfl_xor(ls2, 8, 16);
        if ((t & 15) == 0) {
            atomicAdd(&sum_ws[b * Cc + c0 + row], ls);
            atomicAdd(&sumsq_ws[b * Cc + c0 + row], ls2);
        }
    }
    __syncthreads();
#pragma unroll
    for (int i = 0; i < 2; i++) {
        int id = i * 256 + t;
        int nl = id >> 3, cg = id & 7;
        bf16x8 o;
#pragma unroll
        for (int j = 0; j < 8; j++) o[j] = __bfloat16_as_short(tile[cg * 8 + j][nl]);
        *(bf16x8*)(x_t + ((size_t)(b * Nn + n0 + nl)) * Cc + c0 + cg * 8) = o;
    }
}

// ---------------- W -> bf16 frag-block layout (run once, 5 blocks) ----------------
// w_bf layout: [ct 5][frag 32 = kchunk*4+cg][lane 64][8 elems]
__global__ __launch_bounds__(256) void wconv_kernel(
    const float* __restrict__ Wq, const float* __restrict__ Wk, const float* __restrict__ Wv,
    __hip_bfloat16* __restrict__ w_bf)
{
    const int ct = blockIdx.x;
    const int t = threadIdx.x;
#pragma unroll
    for (int i = 0; i < 8; i++) {
        int g = i * 256 + t;
        int row = g >> 5, c8 = g & 31;
        int c0 = c8 * 8;
        int grow = ct * 64 + row;
        const float* src;
        if (grow < 32)       src = Wq + (size_t)grow * Cc + c0;
        else if (grow < 64)  src = Wk + (size_t)(grow - 32) * Cc + c0;
        else                 src = Wv + (size_t)(grow - 64) * Cc + c0;
        float4 v0 = *(const float4*)src;
        float4 v1 = *(const float4*)(src + 4);
        bf16x8 o;
        o[0] = __bfloat16_as_short(__float2bfloat16(v0.x));
        o[1] = __bfloat16_as_short(__float2bfloat16(v0.y));
        o[2] = __bfloat16_as_short(__float2bfloat16(v0.z));
        o[3] = __bfloat16_as_short(__float2bfloat16(v0.w));
        o[4] = __bfloat16_as_short(__float2bfloat16(v1.x));
        o[5] = __bfloat16_as_short(__float2bfloat16(v1.y));
        o[6] = __bfloat16_as_short(__float2bfloat16(v1.z));
        o[7] = __bfloat16_as_short(__float2bfloat16(v1.w));
        int kchunk = c0 >> 5, qd = (c0 & 31) >> 3, cg = row >> 4, rl = row & 15;
        *(bf16x8*)(w_bf + ((size_t)ct * 32 + kchunk * 4 + cg) * 512 + (qd * 16 + rl) * 8) = o;
    }
}

// ---------------- MFMA projection ----------------
__global__ __launch_bounds__(256, 2) void proj_kernel(
    const __hip_bfloat16* __restrict__ x_t, const __hip_bfloat16* __restrict__ w_bf,
    const float* __restrict__ bq, const float* __restrict__ bk, const float* __restrict__ bv,
    __hip_bfloat16* __restrict__ q_ws, __hip_bfloat16* __restrict__ k_ws,
    __hip_bfloat16* __restrict__ v_ws)
{
    __shared__ __hip_bfloat16 ldsX[32 * 512];
    __shared__ __hip_bfloat16 ldsW[32 * 512];

    const int n0 = blockIdx.x * 64;
    const int ct = blockIdx.y;
    const int b  = blockIdx.z;
    const int t = threadIdx.x;
    const int w = t >> 6, lane = t & 63, quad = lane >> 4, l15 = lane & 15;

#pragma unroll
    for (int j = 0; j < 8; j++) {
        int idx = w * 8 + j;
        int kchunk = idx >> 2, ngrp = idx & 3;
        glds16(x_t + ((size_t)(b * Nn + n0 + ngrp * 16 + l15)) * Cc + kchunk * 32 + quad * 8,
               ldsX + idx * 512);
        glds16(w_bf + ((size_t)ct * 32 + idx) * 512 + lane * 8, ldsW + idx * 512);
    }
    __syncthreads();

    f32x4 acc[4];
#pragma unroll
    for (int cg = 0; cg < 4; cg++) {
        int gcol = ct * 64 + cg * 16 + l15;
        float bias = (gcol < 32) ? bq[gcol] : (gcol < 64 ? bk[gcol - 32] : bv[gcol - 64]);
        acc[cg] = (f32x4){bias, bias, bias, bias};
    }

#pragma unroll
    for (int kchunk = 0; kchunk < 8; kchunk++) {
        bf16x8 a = *(const bf16x8*)(ldsX + ((kchunk * 4 + w) * 64 + lane) * 8);
#pragma unroll
        for (int cg = 0; cg < 4; cg++) {
            bf16x8 bw = *(const bf16x8*)(ldsW + ((kchunk * 4 + cg) * 64 + lane) * 8);
            acc[cg] = __builtin_amdgcn_mfma_f32_16x16x32_bf16(a, bw, acc[cg], 0, 0, 0);
        }
    }

#pragma unroll
    for (int cg = 0; cg < 4; cg++) {
        int gcol = ct * 64 + cg * 16 + l15;
        int nb = n0 + w * 16 + quad * 4;
        if (gcol < 64) {
            __hip_bfloat16* dst = (gcol < 32) ? q_ws : k_ws;
            int d = gcol & 31;
#pragma unroll
            for (int r = 0; r < 4; r++)
                dst[((size_t)(b * Nn + nb + r)) * Dd + d] = __float2bfloat16(acc[cg][r]);
        } else {
            int c = gcol - 64;
            bf16x4 o;
#pragma unroll
            for (int r = 0; r < 4; r++) o[r] = __bfloat16_as_short(__float2bfloat16(acc[cg][r]));
            *(bf16x4*)(v_ws + ((size_t)(b * Cc + c)) * Nn + nb) = o;
        }
    }
}

// ---------------- SE gate MLP ----------------
__global__ __launch_bounds__(256) void gate_kernel(
    const float* __restrict__ sum_ws, const float* __restrict__ sumsq_ws,
    const float* __restrict__ W1, const float* __restrict__ W2,
    const float* __restrict__ lamb, float* __restrict__ coef)
{
    int b = blockIdx.x;
    __shared__ float inp[2 * Cc];
    __shared__ float h[32];
    int t = threadIdx.x;
    float s  = sum_ws[b * Cc + t];
    float s2 = sumsq_ws[b * Cc + t];
    float m   = s / Nn;
    float var = (s2 - (float)Nn * m * m) / (float)(Nn - 1);
    inp[t]      = m;
    inp[Cc + t] = sqrtf(fmaxf(var, 0.f));
    __syncthreads();
    if (t < 32) {
        float a = 0.f;
        for (int i = 0; i < 2 * Cc; i++) a += W1[t * (2 * Cc) + i] * inp[i];
        h[t] = fmaxf(a, 0.f);
    }
    __syncthreads();
    float g = 0.f;
#pragma unroll
    for (int r = 0; r < 32; r++) g += W2[t * 32 + r] * h[r];
    float a = 1.f / (1.f + __expf(-g));
    coef[b * Cc + t] = 1.f + lamb[0] * a;
}

// ---------------- flash attention v3 ----------------
// 4 waves; wave w: S rows mf=w (16), then PV over ALL 4 mf x its 4 tcl (c quarter).
// LDS exactly 40 KB -> 4 blocks/CU. K B-frags direct from global (L2-resident).
// P in frag-block layout [mf*2+kc][lane][8] (b128 reads, stride-16B = free).
__global__ __launch_bounds__(256, 4) void attn_kernel(
    const __hip_bfloat16* __restrict__ q_ws, const __hip_bfloat16* __restrict__ k_ws,
    const __hip_bfloat16* __restrict__ v_ws, const float* __restrict__ coef,
    const float* __restrict__ x, const float* __restrict__ gamma_p,
    float* __restrict__ out)
{
    __shared__ __hip_bfloat16 ldsV[32 * 512];   // 32 KB [ch*16+tc][lane][8]
    __shared__ __hip_bfloat16 ldsP[8 * 512];    //  8 KB [mf*2+kc][lane][8]

    const int b  = blockIdx.x & 7;              // XCD-locality swizzle
    const int m0 = (blockIdx.x >> 3) * 64;
    const int t = threadIdx.x;
    const int w = t >> 6, lane = t & 63, quad = lane >> 4, l15 = lane & 15;

    // Q A-fragment for m-frag w
    const bf16x8 aq = *(const bf16x8*)(q_ws + ((size_t)(b * Nn + m0 + w * 16 + l15)) * Dd + quad * 8);

    // V staging: wave w stages frags idx = w*8+j; ch = idx>>4 fixed per wave, tc = tcb+j
    const int vch = (w >> 1), vtcb = (w & 1) * 8;
    const __hip_bfloat16* vbase =
        v_ws + ((size_t)(b * Cc + vtcb * 16 + l15)) * Nn + vch * 32 + quad * 8;
    const __hip_bfloat16* kbase = k_ws + ((size_t)(b * Nn + l15)) * Dd + quad * 8;

    f32x4 acc[4][4];
#pragma unroll
    for (int i = 0; i < 4; i++)
#pragma unroll
        for (int j = 0; j < 4; j++) acc[i][j] = (f32x4){0.f, 0.f, 0.f, 0.f};
    f32x4 accl = (f32x4){0.f, 0.f, 0.f, 0.f};

    bf16x8 ones;
#pragma unroll
    for (int i = 0; i < 8; i++) ones[i] = (short)0x3F80;

    for (int n0 = 0; n0 < Nn; n0 += 64) {
        __syncthreads();   // B1: previous PV reads done
#pragma unroll
        for (int j = 0; j < 8; j++)
            glds16(vbase + n0 + (size_t)j * (16 * Nn), ldsV + (w * 8 + j) * 512);

        // K B-frags direct from global (independent of LDS staging)
        f32x4 s[4];
#pragma unroll
        for (int tt = 0; tt < 4; tt++) {
            bf16x8 bk = *(const bf16x8*)(kbase + (size_t)(n0 + tt * 16) * Dd);
            s[tt] = __builtin_amdgcn_mfma_f32_16x16x32_bf16(aq, bk, (f32x4){0.f,0.f,0.f,0.f}, 0, 0, 0);
        }
        __syncthreads();   // B2: V tiles landed

        // P = exp(S) -> frag-block LDS: value P[m=4q+r][n=tt*16+l15] -> frag (w, tt>>1)
#pragma unroll
        for (int tt = 0; tt < 4; tt++) {
            int nn = (tt & 1) * 16 + l15;
            __hip_bfloat16* pd = ldsP + (w * 2 + (tt >> 1)) * 512
                               + ((nn >> 3) * 16 + quad * 4) * 8 + (nn & 7);
#pragma unroll
            for (int r = 0; r < 4; r++)
                pd[r * 8] = __float2bfloat16(__expf(s[tt][r]));
        }
        __syncthreads();   // B3: P visible

        // O += P V (4 mf x 4 tcl x 2 kc); li += own-row sums
#pragma unroll
        for (int kc = 0; kc < 2; kc++) {
            bf16x8 ap[4];
#pragma unroll
            for (int mf = 0; mf < 4; mf++)
                ap[mf] = *(const bf16x8*)(ldsP + ((mf * 2 + kc) * 64 + lane) * 8);
            accl = __builtin_amdgcn_mfma_f32_16x16x32_bf16(ap[w], ones, accl, 0, 0, 0);
#pragma unroll
            for (int tcl = 0; tcl < 4; tcl++) {
                bf16x8 bv = *(const bf16x8*)(ldsV + ((kc * 16 + w * 4 + tcl) * 64 + lane) * 8);
#pragma unroll
                for (int mf = 0; mf < 4; mf++)
                    acc[mf][tcl] = __builtin_amdgcn_mfma_f32_16x16x32_bf16(ap[mf], bv, acc[mf][tcl], 0, 0, 0);
            }
        }
    }

    // share l across waves (overlay on ldsV, safe after barrier)
    float* ldsL = (float*)ldsV;
    __syncthreads();
    if (l15 == 0) {
#pragma unroll
        for (int r = 0; r < 4; r++) ldsL[w * 16 + quad * 4 + r] = accl[r];
    }
    __syncthreads();
    const float g = gamma_p[0];
    f32x4 inv[4];
#pragma unroll
    for (int mf = 0; mf < 4; mf++) {
        f32x4 lr = *(const f32x4*)(ldsL + mf * 16 + quad * 4);
#pragma unroll
        for (int r = 0; r < 4; r++) inv[mf][r] = g / lr[r];
    }

#pragma unroll
    for (int mf = 0; mf < 4; mf++) {
#pragma unroll
        for (int tcl = 0; tcl < 4; tcl++) {
            int c = (w * 4 + tcl) * 16 + l15;
            float cf = coef[b * Cc + c];
            size_t base = ((size_t)(b * Cc + c)) * Nn + m0 + mf * 16 + quad * 4;
#pragma unroll
            for (int r = 0; r < 4; r++)
                out[base + r] = acc[mf][tcl][r] * inv[mf][r] + cf * x[base + r];
        }
    }
}

extern "C" void kernel_launch(void* const* d_in, const int* in_sizes, int n_in,
                              void* d_out, int out_size, void* d_ws, size_t ws_size,
                              hipStream_t stream) {
    const float* x     = (const float*)d_in[0];
    const float* Wq    = (const float*)d_in[1];
    const float* bq    = (const float*)d_in[2];
    const float* Wk    = (const float*)d_in[3];
    const float* bk    = (const float*)d_in[4];
    const float* Wv    = (const float*)d_in[5];
    const float* bv    = (const float*)d_in[6];
    const float* gamma = (const float*)d_in[7];
    const float* W1    = (const float*)d_in[8];
    const float* W2    = (const float*)d_in[9];
    const float* lamb  = (const float*)d_in[10];
    float* out = (float*)d_out;

    char* ws = (char*)d_ws;
    __hip_bfloat16* q_ws = (__hip_bfloat16*)ws;                       //  2 MB
    __hip_bfloat16* k_ws = (__hip_bfloat16*)(ws + (2u  << 20));       //  2 MB
    __hip_bfloat16* v_ws = (__hip_bfloat16*)(ws + (4u  << 20));       // 16 MB
    __hip_bfloat16* x_t  = (__hip_bfloat16*)(ws + (20u << 20));       // 16 MB
    float* sum_ws   = (float*)(ws + (36u << 20));
    float* sumsq_ws = sum_ws + Bb * Cc;
    float* coef     = sumsq_ws + Bb * Cc;
    __hip_bfloat16* w_bf = (__hip_bfloat16*)(ws + (37u << 20));       // 320 KB

    hipMemsetAsync(sum_ws, 0, 2 * Bb * Cc * sizeof(float), stream);
    wconv_kernel<<<5, 256, 0, stream>>>(Wq, Wk, Wv, w_bf);
    convt_kernel<<<dim3(Nn / 64, Cc / 64, Bb), 256, 0, stream>>>(x, x_t, sum_ws, sumsq_ws);
    proj_kernel<<<dim3(Nn / 64, 5, Bb), 256, 0, stream>>>(x_t, w_bf, bq, bk, bv, q_ws, k_ws, v_ws);
    gate_kernel<<<Bb, 256, 0, stream>>>(sum_ws, sumsq_ws, W1, W2, lamb, coef);
    attn_kernel<<<Bb * (Nn / 64), 256, 0, stream>>>(q_ws, k_ws, v_ws, coef, x, gamma, out);
}

// Round 5
// 466.382 us; speedup vs baseline: 1.5725x; 1.5725x over previous
//
#include <hip/hip_runtime.h>
#include <hip/hip_bf16.h>

#define Bb 8
#define Cc 256
#define Nn 4096
#define Dd 32

typedef short bf16x8 __attribute__((ext_vector_type(8)));
typedef short bf16x4 __attribute__((ext_vector_type(4)));
typedef float f32x4 __attribute__((ext_vector_type(4)));

__device__ __forceinline__ void glds16(const void* g, void* l) {
    __builtin_amdgcn_global_load_lds(
        (const __attribute__((address_space(1))) unsigned int*)g,
        (__attribute__((address_space(3))) unsigned int*)l, 16, 0, 0);
}

// ---------------- transpose-convert x -> x_t[b][n][c] bf16, fused stats ----------------
__global__ __launch_bounds__(256) void convt_kernel(
    const float* __restrict__ x, __hip_bfloat16* __restrict__ x_t,
    float* __restrict__ sum_ws, float* __restrict__ sumsq_ws)
{
    __shared__ __hip_bfloat16 tile[64][68];
    const int n0 = blockIdx.x * 64, c0 = blockIdx.y * 64, b = blockIdx.z;
    const int t = threadIdx.x;

#pragma unroll
    for (int i = 0; i < 4; i++) {
        int id = i * 256 + t;
        int row = id >> 4, col4 = id & 15;
        float4 v = *(const float4*)(x + ((size_t)(b * Cc + c0 + row)) * Nn + n0 + col4 * 4);
        bf16x4 bv;
        bv[0] = __bfloat16_as_short(__float2bfloat16(v.x));
        bv[1] = __bfloat16_as_short(__float2bfloat16(v.y));
        bv[2] = __bfloat16_as_short(__float2bfloat16(v.z));
        bv[3] = __bfloat16_as_short(__float2bfloat16(v.w));
        *(bf16x4*)((void*)&tile[row][col4 * 4]) = bv;
        float ls  = v.x + v.y + v.z + v.w;
        float ls2 = v.x * v.x + v.y * v.y + v.z * v.z + v.w * v.w;
        ls  += __shfl_xor(ls, 1, 16);  ls2 += __shfl_xor(ls2, 1, 16);
        ls  += __shfl_xor(ls, 2, 16);  ls2 += __shfl_xor(ls2, 2, 16);
        ls  += __shfl_xor(ls, 4, 16);  ls2 += __shfl_xor(ls2, 4, 16);
        ls  += __shfl_xor(ls, 8, 16);  ls2 += __shfl_xor(ls2, 8, 16);
        if ((t & 15) == 0) {
            atomicAdd(&sum_ws[b * Cc + c0 + row], ls);
            atomicAdd(&sumsq_ws[b * Cc + c0 + row], ls2);
        }
    }
    __syncthreads();
#pragma unroll
    for (int i = 0; i < 2; i++) {
        int id = i * 256 + t;
        int nl = id >> 3, cg = id & 7;
        bf16x8 o;
#pragma unroll
        for (int j = 0; j < 8; j++) o[j] = __bfloat16_as_short(tile[cg * 8 + j][nl]);
        *(bf16x8*)(x_t + ((size_t)(b * Nn + n0 + nl)) * Cc + c0 + cg * 8) = o;
    }
}

// ---------------- W -> bf16 frag-block layout (run once, 5 blocks) ----------------
__global__ __launch_bounds__(256) void wconv_kernel(
    const float* __restrict__ Wq, const float* __restrict__ Wk, const float* __restrict__ Wv,
    __hip_bfloat16* __restrict__ w_bf)
{
    const int ct = blockIdx.x;
    const int t = threadIdx.x;
#pragma unroll
    for (int i = 0; i < 8; i++) {
        int g = i * 256 + t;
        int row = g >> 5, c8 = g & 31;
        int c0 = c8 * 8;
        int grow = ct * 64 + row;
        const float* src;
        if (grow < 32)       src = Wq + (size_t)grow * Cc + c0;
        else if (grow < 64)  src = Wk + (size_t)(grow - 32) * Cc + c0;
        else                 src = Wv + (size_t)(grow - 64) * Cc + c0;
        float4 v0 = *(const float4*)src;
        float4 v1 = *(const float4*)(src + 4);
        bf16x8 o;
        o[0] = __bfloat16_as_short(__float2bfloat16(v0.x));
        o[1] = __bfloat16_as_short(__float2bfloat16(v0.y));
        o[2] = __bfloat16_as_short(__float2bfloat16(v0.z));
        o[3] = __bfloat16_as_short(__float2bfloat16(v0.w));
        o[4] = __bfloat16_as_short(__float2bfloat16(v1.x));
        o[5] = __bfloat16_as_short(__float2bfloat16(v1.y));
        o[6] = __bfloat16_as_short(__float2bfloat16(v1.z));
        o[7] = __bfloat16_as_short(__float2bfloat16(v1.w));
        int kchunk = c0 >> 5, qd = (c0 & 31) >> 3, cg = row >> 4, rl = row & 15;
        *(bf16x8*)(w_bf + ((size_t)ct * 32 + kchunk * 4 + cg) * 512 + (qd * 16 + rl) * 8) = o;
    }
}

// ---------------- MFMA projection ----------------
__global__ __launch_bounds__(256, 2) void proj_kernel(
    const __hip_bfloat16* __restrict__ x_t, const __hip_bfloat16* __restrict__ w_bf,
    const float* __restrict__ bq, const float* __restrict__ bk, const float* __restrict__ bv,
    __hip_bfloat16* __restrict__ q_ws, __hip_bfloat16* __restrict__ k_ws,
    __hip_bfloat16* __restrict__ v_ws)
{
    __shared__ __hip_bfloat16 ldsX[32 * 512];
    __shared__ __hip_bfloat16 ldsW[32 * 512];

    const int n0 = blockIdx.x * 64;
    const int ct = blockIdx.y;
    const int b  = blockIdx.z;
    const int t = threadIdx.x;
    const int w = t >> 6, lane = t & 63, quad = lane >> 4, l15 = lane & 15;

#pragma unroll
    for (int j = 0; j < 8; j++) {
        int idx = w * 8 + j;
        int kchunk = idx >> 2, ngrp = idx & 3;
        glds16(x_t + ((size_t)(b * Nn + n0 + ngrp * 16 + l15)) * Cc + kchunk * 32 + quad * 8,
               ldsX + idx * 512);
        glds16(w_bf + ((size_t)ct * 32 + idx) * 512 + lane * 8, ldsW + idx * 512);
    }
    __syncthreads();

    f32x4 acc[4];
#pragma unroll
    for (int cg = 0; cg < 4; cg++) {
        int gcol = ct * 64 + cg * 16 + l15;
        float bias = (gcol < 32) ? bq[gcol] : (gcol < 64 ? bk[gcol - 32] : bv[gcol - 64]);
        acc[cg] = (f32x4){bias, bias, bias, bias};
    }

#pragma unroll
    for (int kchunk = 0; kchunk < 8; kchunk++) {
        bf16x8 a = *(const bf16x8*)(ldsX + ((kchunk * 4 + w) * 64 + lane) * 8);
#pragma unroll
        for (int cg = 0; cg < 4; cg++) {
            bf16x8 bw = *(const bf16x8*)(ldsW + ((kchunk * 4 + cg) * 64 + lane) * 8);
            acc[cg] = __builtin_amdgcn_mfma_f32_16x16x32_bf16(a, bw, acc[cg], 0, 0, 0);
        }
    }

#pragma unroll
    for (int cg = 0; cg < 4; cg++) {
        int gcol = ct * 64 + cg * 16 + l15;
        int nb = n0 + w * 16 + quad * 4;
        if (gcol < 64) {
            __hip_bfloat16* dst = (gcol < 32) ? q_ws : k_ws;
            int d = gcol & 31;
#pragma unroll
            for (int r = 0; r < 4; r++)
                dst[((size_t)(b * Nn + nb + r)) * Dd + d] = __float2bfloat16(acc[cg][r]);
        } else {
            int c = gcol - 64;
            bf16x4 o;
#pragma unroll
            for (int r = 0; r < 4; r++) o[r] = __bfloat16_as_short(__float2bfloat16(acc[cg][r]));
            *(bf16x4*)(v_ws + ((size_t)(b * Cc + c)) * Nn + nb) = o;
        }
    }
}

// ---------------- SE gate MLP ----------------
__global__ __launch_bounds__(256) void gate_kernel(
    const float* __restrict__ sum_ws, const float* __restrict__ sumsq_ws,
    const float* __restrict__ W1, const float* __restrict__ W2,
    const float* __restrict__ lamb, float* __restrict__ coef)
{
    int b = blockIdx.x;
    __shared__ float inp[2 * Cc];
    __shared__ float h[32];
    int t = threadIdx.x;
    float s  = sum_ws[b * Cc + t];
    float s2 = sumsq_ws[b * Cc + t];
    float m   = s / Nn;
    float var = (s2 - (float)Nn * m * m) / (float)(Nn - 1);
    inp[t]      = m;
    inp[Cc + t] = sqrtf(fmaxf(var, 0.f));
    __syncthreads();
    if (t < 32) {
        float a = 0.f;
        for (int i = 0; i < 2 * Cc; i++) a += W1[t * (2 * Cc) + i] * inp[i];
        h[t] = fmaxf(a, 0.f);
    }
    __syncthreads();
    float g = 0.f;
#pragma unroll
    for (int r = 0; r < 32; r++) g += W2[t * 32 + r] * h[r];
    float a = 1.f / (1.f + __expf(-g));
    coef[b * Cc + t] = 1.f + lamb[0] * a;
}

// ---------------- flash attention v3b ----------------
// R4 dataflow with R3 register budget: __launch_bounds__(256,2) -> ~80-100 VGPR,
// no AGPR-copy storm (R4's (256,4) capped VGPR=64 -> VALUBusy 61%, 4x slower).
// 4 waves; wave w: S rows mf=w; PV over all 4 mf x its 4 tcl (c quarter).
// K B-frags direct from global (256 KB/batch, L1/L2-resident, pre-barrier overlap).
__global__ __launch_bounds__(256, 2) void attn_kernel(
    const __hip_bfloat16* __restrict__ q_ws, const __hip_bfloat16* __restrict__ k_ws,
    const __hip_bfloat16* __restrict__ v_ws, const float* __restrict__ coef,
    const float* __restrict__ x, const float* __restrict__ gamma_p,
    float* __restrict__ out)
{
    __shared__ __hip_bfloat16 ldsV[32 * 512];   // 32 KB [ch*16+tc][lane][8]
    __shared__ __hip_bfloat16 ldsP[8 * 512];    //  8 KB [mf*2+kc][lane][8]

    const int b  = blockIdx.x & 7;              // XCD-locality swizzle
    const int m0 = (blockIdx.x >> 3) * 64;
    const int t = threadIdx.x;
    const int w = t >> 6, lane = t & 63, quad = lane >> 4, l15 = lane & 15;

    const bf16x8 aq = *(const bf16x8*)(q_ws + ((size_t)(b * Nn + m0 + w * 16 + l15)) * Dd + quad * 8);

    const int vch = (w >> 1), vtcb = (w & 1) * 8;
    const __hip_bfloat16* vbase =
        v_ws + ((size_t)(b * Cc + vtcb * 16 + l15)) * Nn + vch * 32 + quad * 8;
    const __hip_bfloat16* kbase = k_ws + ((size_t)(b * Nn + l15)) * Dd + quad * 8;

    f32x4 acc[4][4];
#pragma unroll
    for (int i = 0; i < 4; i++)
#pragma unroll
        for (int j = 0; j < 4; j++) acc[i][j] = (f32x4){0.f, 0.f, 0.f, 0.f};
    f32x4 accl = (f32x4){0.f, 0.f, 0.f, 0.f};

    bf16x8 ones;
#pragma unroll
    for (int i = 0; i < 8; i++) ones[i] = (short)0x3F80;

    for (int n0 = 0; n0 < Nn; n0 += 64) {
        __syncthreads();   // B1: previous PV reads done
#pragma unroll
        for (int j = 0; j < 8; j++)
            glds16(vbase + n0 + (size_t)j * (16 * Nn), ldsV + (w * 8 + j) * 512);

        // K B-frags direct from global (independent of V DMA -> overlaps it)
        f32x4 s[4];
#pragma unroll
        for (int tt = 0; tt < 4; tt++) {
            bf16x8 bk = *(const bf16x8*)(kbase + (size_t)(n0 + tt * 16) * Dd);
            s[tt] = __builtin_amdgcn_mfma_f32_16x16x32_bf16(aq, bk, (f32x4){0.f,0.f,0.f,0.f}, 0, 0, 0);
        }
        __syncthreads();   // B2: V tiles landed

        // P = exp(S) -> frag-block LDS
#pragma unroll
        for (int tt = 0; tt < 4; tt++) {
            int nn = (tt & 1) * 16 + l15;
            __hip_bfloat16* pd = ldsP + (w * 2 + (tt >> 1)) * 512
                               + ((nn >> 3) * 16 + quad * 4) * 8 + (nn & 7);
#pragma unroll
            for (int r = 0; r < 4; r++)
                pd[r * 8] = __float2bfloat16(__expf(s[tt][r]));
        }
        __syncthreads();   // B3: P visible

        // O += P V (4 mf x 4 tcl x 2 kc); li += own-row sums
#pragma unroll
        for (int kc = 0; kc < 2; kc++) {
            bf16x8 ap[4];
#pragma unroll
            for (int mf = 0; mf < 4; mf++)
                ap[mf] = *(const bf16x8*)(ldsP + ((mf * 2 + kc) * 64 + lane) * 8);
            accl = __builtin_amdgcn_mfma_f32_16x16x32_bf16(ap[w], ones, accl, 0, 0, 0);
#pragma unroll
            for (int tcl = 0; tcl < 4; tcl++) {
                bf16x8 bv = *(const bf16x8*)(ldsV + ((kc * 16 + w * 4 + tcl) * 64 + lane) * 8);
#pragma unroll
                for (int mf = 0; mf < 4; mf++)
                    acc[mf][tcl] = __builtin_amdgcn_mfma_f32_16x16x32_bf16(ap[mf], bv, acc[mf][tcl], 0, 0, 0);
            }
        }
    }

    // share l across waves (overlay on ldsV, safe after barrier)
    float* ldsL = (float*)ldsV;
    __syncthreads();
    if (l15 == 0) {
#pragma unroll
        for (int r = 0; r < 4; r++) ldsL[w * 16 + quad * 4 + r] = accl[r];
    }
    __syncthreads();
    const float g = gamma_p[0];
    f32x4 inv[4];
#pragma unroll
    for (int mf = 0; mf < 4; mf++) {
        f32x4 lr = *(const f32x4*)(ldsL + mf * 16 + quad * 4);
#pragma unroll
        for (int r = 0; r < 4; r++) inv[mf][r] = g / lr[r];
    }

#pragma unroll
    for (int mf = 0; mf < 4; mf++) {
#pragma unroll
        for (int tcl = 0; tcl < 4; tcl++) {
            int c = (w * 4 + tcl) * 16 + l15;
            float cf = coef[b * Cc + c];
            size_t base = ((size_t)(b * Cc + c)) * Nn + m0 + mf * 16 + quad * 4;
#pragma unroll
            for (int r = 0; r < 4; r++)
                out[base + r] = acc[mf][tcl][r] * inv[mf][r] + cf * x[base + r];
        }
    }
}

extern "C" void kernel_launch(void* const* d_in, const int* in_sizes, int n_in,
                              void* d_out, int out_size, void* d_ws, size_t ws_size,
                              hipStream_t stream) {
    const float* x     = (const float*)d_in[0];
    const float* Wq    = (const float*)d_in[1];
    const float* bq    = (const float*)d_in[2];
    const float* Wk    = (const float*)d_in[3];
    const float* bk    = (const float*)d_in[4];
    const float* Wv    = (const float*)d_in[5];
    const float* bv    = (const float*)d_in[6];
    const float* gamma = (const float*)d_in[7];
    const float* W1    = (const float*)d_in[8];
    const float* W2    = (const float*)d_in[9];
    const float* lamb  = (const float*)d_in[10];
    float* out = (float*)d_out;

    char* ws = (char*)d_ws;
    __hip_bfloat16* q_ws = (__hip_bfloat16*)ws;                       //  2 MB
    __hip_bfloat16* k_ws = (__hip_bfloat16*)(ws + (2u  << 20));       //  2 MB
    __hip_bfloat16* v_ws = (__hip_bfloat16*)(ws + (4u  << 20));       // 16 MB
    __hip_bfloat16* x_t  = (__hip_bfloat16*)(ws + (20u << 20));       // 16 MB
    float* sum_ws   = (float*)(ws + (36u << 20));
    float* sumsq_ws = sum_ws + Bb * Cc;
    float* coef     = sumsq_ws + Bb * Cc;
    __hip_bfloat16* w_bf = (__hip_bfloat16*)(ws + (37u << 20));       // 320 KB

    hipMemsetAsync(sum_ws, 0, 2 * Bb * Cc * sizeof(float), stream);
    wconv_kernel<<<5, 256, 0, stream>>>(Wq, Wk, Wv, w_bf);
    convt_kernel<<<dim3(Nn / 64, Cc / 64, Bb), 256, 0, stream>>>(x, x_t, sum_ws, sumsq_ws);
    proj_kernel<<<dim3(Nn / 64, 5, Bb), 256, 0, stream>>>(x_t, w_bf, bq, bk, bv, q_ws, k_ws, v_ws);
    gate_kernel<<<Bb, 256, 0, stream>>>(sum_ws, sumsq_ws, W1, W2, lamb, coef);
    attn_kernel<<<Bb * (Nn / 64), 256, 0, stream>>>(q_ws, k_ws, v_ws, coef, x, gamma, out);
}

// Round 6
// 282.779 us; speedup vs baseline: 2.5935x; 1.6493x over previous
//
#include <hip/hip_runtime.h>
#include <hip/hip_bf16.h>

#define Bb 8
#define Cc 256
#define Nn 4096
#define Dd 32

typedef short bf16x8 __attribute__((ext_vector_type(8)));
typedef short bf16x4 __attribute__((ext_vector_type(4)));
typedef float f32x4 __attribute__((ext_vector_type(4)));

__device__ __forceinline__ void glds16(const void* g, void* l) {
    __builtin_amdgcn_global_load_lds(
        (const __attribute__((address_space(1))) unsigned int*)g,
        (__attribute__((address_space(3))) unsigned int*)l, 16, 0, 0);
}

// ---------------- transpose-convert x -> x_t[b][n][c] bf16, fused stats ----------------
__global__ __launch_bounds__(256) void convt_kernel(
    const float* __restrict__ x, __hip_bfloat16* __restrict__ x_t,
    float* __restrict__ sum_ws, float* __restrict__ sumsq_ws)
{
    __shared__ __hip_bfloat16 tile[64][68];
    const int n0 = blockIdx.x * 64, c0 = blockIdx.y * 64, b = blockIdx.z;
    const int t = threadIdx.x;

#pragma unroll
    for (int i = 0; i < 4; i++) {
        int id = i * 256 + t;
        int row = id >> 4, col4 = id & 15;
        float4 v = *(const float4*)(x + ((size_t)(b * Cc + c0 + row)) * Nn + n0 + col4 * 4);
        bf16x4 bv;
        bv[0] = __bfloat16_as_short(__float2bfloat16(v.x));
        bv[1] = __bfloat16_as_short(__float2bfloat16(v.y));
        bv[2] = __bfloat16_as_short(__float2bfloat16(v.z));
        bv[3] = __bfloat16_as_short(__float2bfloat16(v.w));
        *(bf16x4*)((void*)&tile[row][col4 * 4]) = bv;
        float ls  = v.x + v.y + v.z + v.w;
        float ls2 = v.x * v.x + v.y * v.y + v.z * v.z + v.w * v.w;
        ls  += __shfl_xor(ls, 1, 16);  ls2 += __shfl_xor(ls2, 1, 16);
        ls  += __shfl_xor(ls, 2, 16);  ls2 += __shfl_xor(ls2, 2, 16);
        ls  += __shfl_xor(ls, 4, 16);  ls2 += __shfl_xor(ls2, 4, 16);
        ls  += __shfl_xor(ls, 8, 16);  ls2 += __shfl_xor(ls2, 8, 16);
        if ((t & 15) == 0) {
            atomicAdd(&sum_ws[b * Cc + c0 + row], ls);
            atomicAdd(&sumsq_ws[b * Cc + c0 + row], ls2);
        }
    }
    __syncthreads();
#pragma unroll
    for (int i = 0; i < 2; i++) {
        int id = i * 256 + t;
        int nl = id >> 3, cg = id & 7;
        bf16x8 o;
#pragma unroll
        for (int j = 0; j < 8; j++) o[j] = __bfloat16_as_short(tile[cg * 8 + j][nl]);
        *(bf16x8*)(x_t + ((size_t)(b * Nn + n0 + nl)) * Cc + c0 + cg * 8) = o;
    }
}

// ---------------- W -> bf16 frag-block layout (run once, 5 blocks) ----------------
__global__ __launch_bounds__(256) void wconv_kernel(
    const float* __restrict__ Wq, const float* __restrict__ Wk, const float* __restrict__ Wv,
    __hip_bfloat16* __restrict__ w_bf)
{
    const int ct = blockIdx.x;
    const int t = threadIdx.x;
#pragma unroll
    for (int i = 0; i < 8; i++) {
        int g = i * 256 + t;
        int row = g >> 5, c8 = g & 31;
        int c0 = c8 * 8;
        int grow = ct * 64 + row;
        const float* src;
        if (grow < 32)       src = Wq + (size_t)grow * Cc + c0;
        else if (grow < 64)  src = Wk + (size_t)(grow - 32) * Cc + c0;
        else                 src = Wv + (size_t)(grow - 64) * Cc + c0;
        float4 v0 = *(const float4*)src;
        float4 v1 = *(const float4*)(src + 4);
        bf16x8 o;
        o[0] = __bfloat16_as_short(__float2bfloat16(v0.x));
        o[1] = __bfloat16_as_short(__float2bfloat16(v0.y));
        o[2] = __bfloat16_as_short(__float2bfloat16(v0.z));
        o[3] = __bfloat16_as_short(__float2bfloat16(v0.w));
        o[4] = __bfloat16_as_short(__float2bfloat16(v1.x));
        o[5] = __bfloat16_as_short(__float2bfloat16(v1.y));
        o[6] = __bfloat16_as_short(__float2bfloat16(v1.z));
        o[7] = __bfloat16_as_short(__float2bfloat16(v1.w));
        int kchunk = c0 >> 5, qd = (c0 & 31) >> 3, cg = row >> 4, rl = row & 15;
        *(bf16x8*)(w_bf + ((size_t)ct * 32 + kchunk * 4 + cg) * 512 + (qd * 16 + rl) * 8) = o;
    }
}

// ---------------- MFMA projection ----------------
__global__ __launch_bounds__(256, 2) void proj_kernel(
    const __hip_bfloat16* __restrict__ x_t, const __hip_bfloat16* __restrict__ w_bf,
    const float* __restrict__ bq, const float* __restrict__ bk, const float* __restrict__ bv,
    __hip_bfloat16* __restrict__ q_ws, __hip_bfloat16* __restrict__ k_ws,
    __hip_bfloat16* __restrict__ v_ws)
{
    __shared__ __hip_bfloat16 ldsX[32 * 512];
    __shared__ __hip_bfloat16 ldsW[32 * 512];

    const int n0 = blockIdx.x * 64;
    const int ct = blockIdx.y;
    const int b  = blockIdx.z;
    const int t = threadIdx.x;
    const int w = t >> 6, lane = t & 63, quad = lane >> 4, l15 = lane & 15;

#pragma unroll
    for (int j = 0; j < 8; j++) {
        int idx = w * 8 + j;
        int kchunk = idx >> 2, ngrp = idx & 3;
        glds16(x_t + ((size_t)(b * Nn + n0 + ngrp * 16 + l15)) * Cc + kchunk * 32 + quad * 8,
               ldsX + idx * 512);
        glds16(w_bf + ((size_t)ct * 32 + idx) * 512 + lane * 8, ldsW + idx * 512);
    }
    __syncthreads();

    f32x4 acc[4];
#pragma unroll
    for (int cg = 0; cg < 4; cg++) {
        int gcol = ct * 64 + cg * 16 + l15;
        float bias = (gcol < 32) ? bq[gcol] : (gcol < 64 ? bk[gcol - 32] : bv[gcol - 64]);
        acc[cg] = (f32x4){bias, bias, bias, bias};
    }

#pragma unroll
    for (int kchunk = 0; kchunk < 8; kchunk++) {
        bf16x8 a = *(const bf16x8*)(ldsX + ((kchunk * 4 + w) * 64 + lane) * 8);
#pragma unroll
        for (int cg = 0; cg < 4; cg++) {
            bf16x8 bw = *(const bf16x8*)(ldsW + ((kchunk * 4 + cg) * 64 + lane) * 8);
            acc[cg] = __builtin_amdgcn_mfma_f32_16x16x32_bf16(a, bw, acc[cg], 0, 0, 0);
        }
    }

#pragma unroll
    for (int cg = 0; cg < 4; cg++) {
        int gcol = ct * 64 + cg * 16 + l15;
        int nb = n0 + w * 16 + quad * 4;
        if (gcol < 64) {
            __hip_bfloat16* dst = (gcol < 32) ? q_ws : k_ws;
            int d = gcol & 31;
#pragma unroll
            for (int r = 0; r < 4; r++)
                dst[((size_t)(b * Nn + nb + r)) * Dd + d] = __float2bfloat16(acc[cg][r]);
        } else {
            int c = gcol - 64;
            bf16x4 o;
#pragma unroll
            for (int r = 0; r < 4; r++) o[r] = __bfloat16_as_short(__float2bfloat16(acc[cg][r]));
            *(bf16x4*)(v_ws + ((size_t)(b * Cc + c)) * Nn + nb) = o;
        }
    }
}

// ---------------- SE gate MLP ----------------
__global__ __launch_bounds__(256) void gate_kernel(
    const float* __restrict__ sum_ws, const float* __restrict__ sumsq_ws,
    const float* __restrict__ W1, const float* __restrict__ W2,
    const float* __restrict__ lamb, float* __restrict__ coef)
{
    int b = blockIdx.x;
    __shared__ float inp[2 * Cc];
    __shared__ float h[32];
    int t = threadIdx.x;
    float s  = sum_ws[b * Cc + t];
    float s2 = sumsq_ws[b * Cc + t];
    float m   = s / Nn;
    float var = (s2 - (float)Nn * m * m) / (float)(Nn - 1);
    inp[t]      = m;
    inp[Cc + t] = sqrtf(fmaxf(var, 0.f));
    __syncthreads();
    if (t < 32) {
        float a = 0.f;
        for (int i = 0; i < 2 * Cc; i++) a += W1[t * (2 * Cc) + i] * inp[i];
        h[t] = fmaxf(a, 0.f);
    }
    __syncthreads();
    float g = 0.f;
#pragma unroll
    for (int r = 0; r < 32; r++) g += W2[t * 32 + r] * h[r];
    float a = 1.f / (1.f + __expf(-g));
    coef[b * Cc + t] = 1.f + lamb[0] * a;
}

// ---------------- flash attention v4 ----------------
// R3's proven structure (acc[2][8], P shared via LDS, K from LDS, (256,2) ->
// ~84 VGPR, no AGPR storm) + two changes:
//  1. K staged in 128-n slabs, double-buffered, prefetched 1 slab ahead ->
//     S-MFMA never waits on this iter's DMA -> the post-DMA barrier moves
//     AFTER the S/exp/P phase (3 barriers -> 2, DMA flight hidden under S).
//  2. XCD swizzle b=blockIdx&7 (R5: FETCH 92->32 MB, V L2-resident).
// R4/R5 lessons kept OUT: no global K B-frags (VALU storm), no (256,4).
__global__ __launch_bounds__(256, 2) void attn_kernel(
    const __hip_bfloat16* __restrict__ q_ws, const __hip_bfloat16* __restrict__ k_ws,
    const __hip_bfloat16* __restrict__ v_ws, const float* __restrict__ coef,
    const float* __restrict__ x, const float* __restrict__ gamma_p,
    float* __restrict__ out)
{
    __shared__ __hip_bfloat16 ldsV[32 * 512];      // 32 KB [ch*16+tc][lane][8]
    __shared__ __hip_bfloat16 ldsK[2][8 * 512];    // 16 KB: 2 slabs x 8 n-tiles
    __shared__ __hip_bfloat16 ldsP[4 * 16 * 72];   //  9 KB [mfrag][m 16][72]

    const int b  = blockIdx.x & 7;                 // XCD-locality swizzle
    const int m0 = (blockIdx.x >> 3) * 64;
    const int t = threadIdx.x;
    const int w = t >> 6, lane = t & 63, quad = lane >> 4, l15 = lane & 15;
    const int mf0 = (w >> 1) * 2, chalf = w & 1;

    // Q A-fragment for m-frag w (held all kernel)
    const bf16x8 aq = *(const bf16x8*)(q_ws + ((size_t)(b * Nn + m0 + w * 16 + l15)) * Dd + quad * 8);

    // V staging: wave w stages frags idx = w*8+j (idx = ch*16+tc)
    const __hip_bfloat16* vsrc[8];
#pragma unroll
    for (int j = 0; j < 8; j++) {
        int idx = w * 8 + j;
        int ch = idx >> 4, tc = idx & 15;
        vsrc[j] = v_ws + ((size_t)(b * Cc + tc * 16 + l15)) * Nn + ch * 32 + quad * 8;
    }
    // K staging: slab s covers n in [128s,128s+128); wave w stages frags w*2, w*2+1
    const __hip_bfloat16* ksrc = k_ws + ((size_t)(b * Nn + w * 32 + l15)) * Dd + quad * 8;

    // prestage slab 0 (drained by the loop's first B1)
    glds16(ksrc,            ldsK[0] + (w * 2    ) * 512);
    glds16(ksrc + 16 * Dd,  ldsK[0] + (w * 2 + 1) * 512);

    f32x4 acc[2][8];
#pragma unroll
    for (int i = 0; i < 2; i++)
#pragma unroll
        for (int j = 0; j < 8; j++) acc[i][j] = (f32x4){0.f, 0.f, 0.f, 0.f};
    f32x4 accl[2] = {(f32x4){0.f,0.f,0.f,0.f}, (f32x4){0.f,0.f,0.f,0.f}};

    bf16x8 ones;
#pragma unroll
    for (int i = 0; i < 8; i++) ones[i] = (short)0x3F80;

    for (int it = 0; it < Nn / 64; it++) {
        const int n0 = it * 64;
        __syncthreads();   // B1: prior PV reads of ldsV/ldsP done; prior DMAs drained

        // V DMA for this iter (drained at B2, flight hidden under S-phase)
#pragma unroll
        for (int j = 0; j < 8; j++)
            glds16(vsrc[j] + n0, ldsV + (w * 8 + j) * 512);
        // K DMA one slab ahead (consumed 2 iters later)
        if ((it & 1) == 0 && it + 2 < Nn / 64) {
            int s = (it >> 1) + 1;
            glds16(ksrc + (size_t)(s * 128) * Dd,      ldsK[s & 1] + (w * 2    ) * 512);
            glds16(ksrc + (size_t)(s * 128 + 16) * Dd, ldsK[s & 1] + (w * 2 + 1) * 512);
        }

        // S = Q K^T from the already-resident slab
        const __hip_bfloat16* kb = ldsK[(it >> 1) & 1] + (it & 1) * 4 * 512;
        f32x4 s[4];
#pragma unroll
        for (int tt = 0; tt < 4; tt++) {
            bf16x8 bk = *(const bf16x8*)(kb + (tt * 64 + lane) * 8);
            s[tt] = __builtin_amdgcn_mfma_f32_16x16x32_bf16(aq, bk, (f32x4){0.f,0.f,0.f,0.f}, 0, 0, 0);
        }
        // P = exp(S) (no max shift; logits bounded ~40) -> shared P, frag w
        __hip_bfloat16* myP = ldsP + w * (16 * 72);
#pragma unroll
        for (int tt = 0; tt < 4; tt++)
#pragma unroll
            for (int r = 0; r < 4; r++)
                myP[(quad * 4 + r) * 72 + tt * 16 + l15] = __float2bfloat16(__expf(s[tt][r]));

        __syncthreads();   // B2: V landed, P visible

        // O += P V ; li += P . 1   (wave: m-frags {mf0,mf0+1} x c-half chalf)
#pragma unroll
        for (int ch = 0; ch < 2; ch++) {
            bf16x8 ap0 = *(const bf16x8*)(ldsP + (size_t)(mf0    ) * (16*72) + l15 * 72 + ch * 32 + quad * 8);
            bf16x8 ap1 = *(const bf16x8*)(ldsP + (size_t)(mf0 + 1) * (16*72) + l15 * 72 + ch * 32 + quad * 8);
            accl[0] = __builtin_amdgcn_mfma_f32_16x16x32_bf16(ap0, ones, accl[0], 0, 0, 0);
            accl[1] = __builtin_amdgcn_mfma_f32_16x16x32_bf16(ap1, ones, accl[1], 0, 0, 0);
#pragma unroll
            for (int tcl = 0; tcl < 8; tcl++) {
                bf16x8 bv = *(const bf16x8*)(ldsV + ((ch * 16 + chalf * 8 + tcl) * 64 + lane) * 8);
                acc[0][tcl] = __builtin_amdgcn_mfma_f32_16x16x32_bf16(ap0, bv, acc[0][tcl], 0, 0, 0);
                acc[1][tcl] = __builtin_amdgcn_mfma_f32_16x16x32_bf16(ap1, bv, acc[1][tcl], 0, 0, 0);
            }
        }
    }

    // epilogue: out = gamma*O/l + (1 + lamb*a)*x
    const float g = gamma_p[0];
    float inv[2][4];
#pragma unroll
    for (int mfi = 0; mfi < 2; mfi++)
#pragma unroll
        for (int r = 0; r < 4; r++) inv[mfi][r] = g / accl[mfi][r];

#pragma unroll
    for (int mfi = 0; mfi < 2; mfi++) {
#pragma unroll
        for (int tcl = 0; tcl < 8; tcl++) {
            int c = (chalf * 8 + tcl) * 16 + l15;
            float cf = coef[b * Cc + c];
            size_t base = ((size_t)(b * Cc + c)) * Nn + m0 + (mf0 + mfi) * 16 + quad * 4;
#pragma unroll
            for (int r = 0; r < 4; r++)
                out[base + r] = acc[mfi][tcl][r] * inv[mfi][r] + cf * x[base + r];
        }
    }
}

extern "C" void kernel_launch(void* const* d_in, const int* in_sizes, int n_in,
                              void* d_out, int out_size, void* d_ws, size_t ws_size,
                              hipStream_t stream) {
    const float* x     = (const float*)d_in[0];
    const float* Wq    = (const float*)d_in[1];
    const float* bq    = (const float*)d_in[2];
    const float* Wk    = (const float*)d_in[3];
    const float* bk    = (const float*)d_in[4];
    const float* Wv    = (const float*)d_in[5];
    const float* bv    = (const float*)d_in[6];
    const float* gamma = (const float*)d_in[7];
    const float* W1    = (const float*)d_in[8];
    const float* W2    = (const float*)d_in[9];
    const float* lamb  = (const float*)d_in[10];
    float* out = (float*)d_out;

    char* ws = (char*)d_ws;
    __hip_bfloat16* q_ws = (__hip_bfloat16*)ws;                       //  2 MB
    __hip_bfloat16* k_ws = (__hip_bfloat16*)(ws + (2u  << 20));       //  2 MB
    __hip_bfloat16* v_ws = (__hip_bfloat16*)(ws + (4u  << 20));       // 16 MB
    __hip_bfloat16* x_t  = (__hip_bfloat16*)(ws + (20u << 20));       // 16 MB
    float* sum_ws   = (float*)(ws + (36u << 20));
    float* sumsq_ws = sum_ws + Bb * Cc;
    float* coef     = sumsq_ws + Bb * Cc;
    __hip_bfloat16* w_bf = (__hip_bfloat16*)(ws + (37u << 20));       // 320 KB

    hipMemsetAsync(sum_ws, 0, 2 * Bb * Cc * sizeof(float), stream);
    wconv_kernel<<<5, 256, 0, stream>>>(Wq, Wk, Wv, w_bf);
    convt_kernel<<<dim3(Nn / 64, Cc / 64, Bb), 256, 0, stream>>>(x, x_t, sum_ws, sumsq_ws);
    proj_kernel<<<dim3(Nn / 64, 5, Bb), 256, 0, stream>>>(x_t, w_bf, bq, bk, bv, q_ws, k_ws, v_ws);
    gate_kernel<<<Bb, 256, 0, stream>>>(sum_ws, sumsq_ws, W1, W2, lamb, coef);
    attn_kernel<<<Bb * (Nn / 64), 256, 0, stream>>>(q_ws, k_ws, v_ws, coef, x, gamma, out);
}

// Round 8
// 244.442 us; speedup vs baseline: 3.0003x; 1.1568x over previous
//
#include <hip/hip_runtime.h>
#include <hip/hip_bf16.h>

#define Bb 8
#define Cc 256
#define Nn 4096
#define Dd 32

typedef short bf16x8 __attribute__((ext_vector_type(8)));
typedef short bf16x4 __attribute__((ext_vector_type(4)));
typedef float f32x4 __attribute__((ext_vector_type(4)));

__device__ __forceinline__ void glds16(const void* g, void* l) {
    __builtin_amdgcn_global_load_lds(
        (const __attribute__((address_space(1))) unsigned int*)g,
        (__attribute__((address_space(3))) unsigned int*)l, 16, 0, 0);
}

// ---------------- transpose-convert x -> x_t[b][n][c] bf16, fused stats ----------------
__global__ __launch_bounds__(256) void convt_kernel(
    const float* __restrict__ x, __hip_bfloat16* __restrict__ x_t,
    float* __restrict__ sum_ws, float* __restrict__ sumsq_ws)
{
    __shared__ __hip_bfloat16 tile[64][68];
    const int n0 = blockIdx.x * 64, c0 = blockIdx.y * 64, b = blockIdx.z;
    const int t = threadIdx.x;

#pragma unroll
    for (int i = 0; i < 4; i++) {
        int id = i * 256 + t;
        int row = id >> 4, col4 = id & 15;
        float4 v = *(const float4*)(x + ((size_t)(b * Cc + c0 + row)) * Nn + n0 + col4 * 4);
        bf16x4 bv;
        bv[0] = __bfloat16_as_short(__float2bfloat16(v.x));
        bv[1] = __bfloat16_as_short(__float2bfloat16(v.y));
        bv[2] = __bfloat16_as_short(__float2bfloat16(v.z));
        bv[3] = __bfloat16_as_short(__float2bfloat16(v.w));
        *(bf16x4*)((void*)&tile[row][col4 * 4]) = bv;
        float ls  = v.x + v.y + v.z + v.w;
        float ls2 = v.x * v.x + v.y * v.y + v.z * v.z + v.w * v.w;
        ls  += __shfl_xor(ls, 1, 16);  ls2 += __shfl_xor(ls2, 1, 16);
        ls  += __shfl_xor(ls, 2, 16);  ls2 += __shfl_xor(ls2, 2, 16);
        ls  += __shfl_xor(ls, 4, 16);  ls2 += __shfl_xor(ls2, 4, 16);
        ls  += __shfl_xor(ls, 8, 16);  ls2 += __shfl_xor(ls2, 8, 16);
        if ((t & 15) == 0) {
            atomicAdd(&sum_ws[b * Cc + c0 + row], ls);
            atomicAdd(&sumsq_ws[b * Cc + c0 + row], ls2);
        }
    }
    __syncthreads();
#pragma unroll
    for (int i = 0; i < 2; i++) {
        int id = i * 256 + t;
        int nl = id >> 3, cg = id & 7;
        bf16x8 o;
#pragma unroll
        for (int j = 0; j < 8; j++) o[j] = __bfloat16_as_short(tile[cg * 8 + j][nl]);
        *(bf16x8*)(x_t + ((size_t)(b * Nn + n0 + nl)) * Cc + c0 + cg * 8) = o;
    }
}

// ---------------- W -> bf16 frag-block layout (run once, 5 blocks) ----------------
__global__ __launch_bounds__(256) void wconv_kernel(
    const float* __restrict__ Wq, const float* __restrict__ Wk, const float* __restrict__ Wv,
    __hip_bfloat16* __restrict__ w_bf)
{
    const int ct = blockIdx.x;
    const int t = threadIdx.x;
#pragma unroll
    for (int i = 0; i < 8; i++) {
        int g = i * 256 + t;
        int row = g >> 5, c8 = g & 31;
        int c0 = c8 * 8;
        int grow = ct * 64 + row;
        const float* src;
        if (grow < 32)       src = Wq + (size_t)grow * Cc + c0;
        else if (grow < 64)  src = Wk + (size_t)(grow - 32) * Cc + c0;
        else                 src = Wv + (size_t)(grow - 64) * Cc + c0;
        float4 v0 = *(const float4*)src;
        float4 v1 = *(const float4*)(src + 4);
        bf16x8 o;
        o[0] = __bfloat16_as_short(__float2bfloat16(v0.x));
        o[1] = __bfloat16_as_short(__float2bfloat16(v0.y));
        o[2] = __bfloat16_as_short(__float2bfloat16(v0.z));
        o[3] = __bfloat16_as_short(__float2bfloat16(v0.w));
        o[4] = __bfloat16_as_short(__float2bfloat16(v1.x));
        o[5] = __bfloat16_as_short(__float2bfloat16(v1.y));
        o[6] = __bfloat16_as_short(__float2bfloat16(v1.z));
        o[7] = __bfloat16_as_short(__float2bfloat16(v1.w));
        int kchunk = c0 >> 5, qd = (c0 & 31) >> 3, cg = row >> 4, rl = row & 15;
        *(bf16x8*)(w_bf + ((size_t)ct * 32 + kchunk * 4 + cg) * 512 + (qd * 16 + rl) * 8) = o;
    }
}

// ---------------- MFMA projection ----------------
__global__ __launch_bounds__(256, 2) void proj_kernel(
    const __hip_bfloat16* __restrict__ x_t, const __hip_bfloat16* __restrict__ w_bf,
    const float* __restrict__ bq, const float* __restrict__ bk, const float* __restrict__ bv,
    __hip_bfloat16* __restrict__ q_ws, __hip_bfloat16* __restrict__ k_ws,
    __hip_bfloat16* __restrict__ v_ws)
{
    __shared__ __hip_bfloat16 ldsX[32 * 512];
    __shared__ __hip_bfloat16 ldsW[32 * 512];

    const int n0 = blockIdx.x * 64;
    const int ct = blockIdx.y;
    const int b  = blockIdx.z;
    const int t = threadIdx.x;
    const int w = t >> 6, lane = t & 63, quad = lane >> 4, l15 = lane & 15;

#pragma unroll
    for (int j = 0; j < 8; j++) {
        int idx = w * 8 + j;
        int kchunk = idx >> 2, ngrp = idx & 3;
        glds16(x_t + ((size_t)(b * Nn + n0 + ngrp * 16 + l15)) * Cc + kchunk * 32 + quad * 8,
               ldsX + idx * 512);
        glds16(w_bf + ((size_t)ct * 32 + idx) * 512 + lane * 8, ldsW + idx * 512);
    }
    __syncthreads();

    f32x4 acc[4];
#pragma unroll
    for (int cg = 0; cg < 4; cg++) {
        int gcol = ct * 64 + cg * 16 + l15;
        float bias = (gcol < 32) ? bq[gcol] : (gcol < 64 ? bk[gcol - 32] : bv[gcol - 64]);
        acc[cg] = (f32x4){bias, bias, bias, bias};
    }

#pragma unroll
    for (int kchunk = 0; kchunk < 8; kchunk++) {
        bf16x8 a = *(const bf16x8*)(ldsX + ((kchunk * 4 + w) * 64 + lane) * 8);
#pragma unroll
        for (int cg = 0; cg < 4; cg++) {
            bf16x8 bw = *(const bf16x8*)(ldsW + ((kchunk * 4 + cg) * 64 + lane) * 8);
            acc[cg] = __builtin_amdgcn_mfma_f32_16x16x32_bf16(a, bw, acc[cg], 0, 0, 0);
        }
    }

#pragma unroll
    for (int cg = 0; cg < 4; cg++) {
        int gcol = ct * 64 + cg * 16 + l15;
        int nb = n0 + w * 16 + quad * 4;
        if (gcol < 64) {
            __hip_bfloat16* dst = (gcol < 32) ? q_ws : k_ws;
            int d = gcol & 31;
#pragma unroll
            for (int r = 0; r < 4; r++)
                dst[((size_t)(b * Nn + nb + r)) * Dd + d] = __float2bfloat16(acc[cg][r]);
        } else {
            int c = gcol - 64;
            bf16x4 o;
#pragma unroll
            for (int r = 0; r < 4; r++) o[r] = __bfloat16_as_short(__float2bfloat16(acc[cg][r]));
            *(bf16x4*)(v_ws + ((size_t)(b * Cc + c)) * Nn + nb) = o;
        }
    }
}

// ---------------- SE gate MLP ----------------
__global__ __launch_bounds__(256) void gate_kernel(
    const float* __restrict__ sum_ws, const float* __restrict__ sumsq_ws,
    const float* __restrict__ W1, const float* __restrict__ W2,
    const float* __restrict__ lamb, float* __restrict__ coef)
{
    int b = blockIdx.x;
    __shared__ float inp[2 * Cc];
    __shared__ float h[32];
    int t = threadIdx.x;
    float s  = sum_ws[b * Cc + t];
    float s2 = sumsq_ws[b * Cc + t];
    float m   = s / Nn;
    float var = (s2 - (float)Nn * m * m) / (float)(Nn - 1);
    inp[t]      = m;
    inp[Cc + t] = sqrtf(fmaxf(var, 0.f));
    __syncthreads();
    if (t < 32) {
        float a = 0.f;
        for (int i = 0; i < 2 * Cc; i++) a += W1[t * (2 * Cc) + i] * inp[i];
        h[t] = fmaxf(a, 0.f);
    }
    __syncthreads();
    float g = 0.f;
#pragma unroll
    for (int r = 0; r < 32; r++) g += W2[t * 32 + r] * h[r];
    float a = 1.f / (1.f + __expf(-g));
    coef[b * Cc + t] = 1.f + lamb[0] * a;
}

// ---------------- flash attention v5b: BM=128, 512 thr, 1 barrier/iter ----------------
// R7 + FIX: __syncthreads() between prestage and loop. R7's bug: iteration 0's
// S-phase ds_read of kbuf0 had NO vmcnt wait after the prestage global_load_lds
// (compiler tracks register deps, not LDS-memory deps of the DMA) -> garbage K
// for the first 128 columns -> absmax 3.86. All other buffer reuses are protected
// by barrier-distance >= 1 full iteration (analysis in R8 notes).
__global__ __launch_bounds__(512, 2) void attn_kernel(
    const __hip_bfloat16* __restrict__ q_ws, const __hip_bfloat16* __restrict__ k_ws,
    const __hip_bfloat16* __restrict__ v_ws, const float* __restrict__ coef,
    const float* __restrict__ x, const float* __restrict__ gamma_p,
    float* __restrict__ out)
{
    extern __shared__ __hip_bfloat16 smem[];
    __hip_bfloat16* vbuf0 = smem;              // 16384 el each
    __hip_bfloat16* vbuf1 = smem + 16384;
    __hip_bfloat16* kbuf0 = smem + 32768;      // 4096 el each (8 frags)
    __hip_bfloat16* kbuf1 = smem + 36864;
    __hip_bfloat16* pbuf0 = smem + 40960;      // 8192 el each (16 frags)
    __hip_bfloat16* pbuf1 = smem + 49152;      // total 57344 el = 114688 B

    const int b  = blockIdx.x & 7;             // XCD-locality swizzle
    const int m0 = (blockIdx.x >> 3) * 128;
    const int t = threadIdx.x;
    const int w = t >> 6, lane = t & 63, quad = lane >> 4, l15 = lane & 15;
    const int mf0 = (w >> 1) * 2, chalf = w & 1;

    // Q A-fragment for m-frag w (held all kernel)
    const bf16x8 aq = *(const bf16x8*)(q_ws + ((size_t)(b * Nn + m0 + w * 16 + l15)) * Dd + quad * 8);

    // V staging: wave w stages frags idx = w*4+j (idx = ch*16+tc)
    const __hip_bfloat16* vsrc[4];
#pragma unroll
    for (int j = 0; j < 4; j++) {
        int idx = w * 4 + j;
        int ch = idx >> 4, tc = idx & 15;
        vsrc[j] = v_ws + ((size_t)(b * Cc + tc * 16 + l15)) * Nn + ch * 32 + quad * 8;
    }
    // K staging: slab s = n[128s..128s+128), 8 frags; wave w stages frag w
    const __hip_bfloat16* ksrc = k_ws + ((size_t)(b * Nn + w * 16 + l15)) * Dd + quad * 8;

    // prestage V(0) + K slab 0
#pragma unroll
    for (int j = 0; j < 4; j++) glds16(vsrc[j], vbuf0 + (w * 4 + j) * 512);
    glds16(ksrc, kbuf0 + w * 512);
    __syncthreads();   // FIX: drain prestage DMAs (vmcnt(0) at barrier) before first use

    f32x4 acc[2][8];
#pragma unroll
    for (int i = 0; i < 2; i++)
#pragma unroll
        for (int j = 0; j < 8; j++) acc[i][j] = (f32x4){0.f, 0.f, 0.f, 0.f};
    f32x4 accl[2] = {(f32x4){0.f,0.f,0.f,0.f}, (f32x4){0.f,0.f,0.f,0.f}};

    bf16x8 ones;
#pragma unroll
    for (int i = 0; i < 8; i++) ones[i] = (short)0x3F80;  // bf16 1.0

    for (int it = 0; it < Nn / 64; it++) {
        // ---- S = Q K^T from resident K slab ----
        const __hip_bfloat16* kb = (((it >> 1) & 1) ? kbuf1 : kbuf0) + (it & 1) * 2048;
        f32x4 s[4];
#pragma unroll
        for (int tt = 0; tt < 4; tt++) {
            bf16x8 bk = *(const bf16x8*)(kb + (tt * 64 + lane) * 8);
            s[tt] = __builtin_amdgcn_mfma_f32_16x16x32_bf16(aq, bk, (f32x4){0.f,0.f,0.f,0.f}, 0, 0, 0);
        }
        // ---- P = exp(S) -> frag-block pbuf[it&1] (A-layout for m-frag w) ----
        __hip_bfloat16* pb = (it & 1) ? pbuf1 : pbuf0;
#pragma unroll
        for (int tt = 0; tt < 4; tt++) {
            int nn = (tt & 1) * 16 + l15;
            __hip_bfloat16* pd = pb + (w * 2 + (tt >> 1)) * 512
                               + ((nn >> 3) * 16 + quad * 4) * 8 + (nn & 7);
#pragma unroll
            for (int r = 0; r < 4; r++)
                pd[r * 8] = __float2bfloat16(__expf(s[tt][r]));
        }

        __syncthreads();  // ONE barrier: V(it)/K landed (>=1 iter in flight), P published,
                          // all waves done with the other V/P buffers from it-1.

        // ---- prefetch next tiles into the other buffers ----
        if (it + 1 < Nn / 64) {
            __hip_bfloat16* vn = ((it + 1) & 1) ? vbuf1 : vbuf0;
#pragma unroll
            for (int j = 0; j < 4; j++)
                glds16(vsrc[j] + (size_t)(it + 1) * 64, vn + (w * 4 + j) * 512);
        }
        if ((it & 1) == 0 && it + 2 < Nn / 64) {
            int sl = (it >> 1) + 1;
            glds16(ksrc + (size_t)(sl * 128) * Dd, ((sl & 1) ? kbuf1 : kbuf0) + w * 512);
        }

        // ---- O += P V ; li += P . 1 ----
        const __hip_bfloat16* vb = (it & 1) ? vbuf1 : vbuf0;
        const __hip_bfloat16* pr = pb;
#pragma unroll
        for (int kc = 0; kc < 2; kc++) {
            bf16x8 ap0 = *(const bf16x8*)(pr + (((mf0    ) * 2 + kc) * 64 + lane) * 8);
            bf16x8 ap1 = *(const bf16x8*)(pr + (((mf0 + 1) * 2 + kc) * 64 + lane) * 8);
            accl[0] = __builtin_amdgcn_mfma_f32_16x16x32_bf16(ap0, ones, accl[0], 0, 0, 0);
            accl[1] = __builtin_amdgcn_mfma_f32_16x16x32_bf16(ap1, ones, accl[1], 0, 0, 0);
#pragma unroll
            for (int tcl = 0; tcl < 8; tcl++) {
                bf16x8 bv = *(const bf16x8*)(vb + ((kc * 16 + chalf * 8 + tcl) * 64 + lane) * 8);
                acc[0][tcl] = __builtin_amdgcn_mfma_f32_16x16x32_bf16(ap0, bv, acc[0][tcl], 0, 0, 0);
                acc[1][tcl] = __builtin_amdgcn_mfma_f32_16x16x32_bf16(ap1, bv, acc[1][tcl], 0, 0, 0);
            }
        }
    }

    // epilogue: out = gamma*O/l + (1 + lamb*a)*x
    const float g = gamma_p[0];
    float inv[2][4];
#pragma unroll
    for (int mfi = 0; mfi < 2; mfi++)
#pragma unroll
        for (int r = 0; r < 4; r++) inv[mfi][r] = g / accl[mfi][r];

#pragma unroll
    for (int mfi = 0; mfi < 2; mfi++) {
#pragma unroll
        for (int tcl = 0; tcl < 8; tcl++) {
            int c = (chalf * 8 + tcl) * 16 + l15;
            float cf = coef[b * Cc + c];
            size_t base = ((size_t)(b * Cc + c)) * Nn + m0 + (mf0 + mfi) * 16 + quad * 4;
#pragma unroll
            for (int r = 0; r < 4; r++)
                out[base + r] = acc[mfi][tcl][r] * inv[mfi][r] + cf * x[base + r];
        }
    }
}

extern "C" void kernel_launch(void* const* d_in, const int* in_sizes, int n_in,
                              void* d_out, int out_size, void* d_ws, size_t ws_size,
                              hipStream_t stream) {
    const float* x     = (const float*)d_in[0];
    const float* Wq    = (const float*)d_in[1];
    const float* bq    = (const float*)d_in[2];
    const float* Wk    = (const float*)d_in[3];
    const float* bk    = (const float*)d_in[4];
    const float* Wv    = (const float*)d_in[5];
    const float* bv    = (const float*)d_in[6];
    const float* gamma = (const float*)d_in[7];
    const float* W1    = (const float*)d_in[8];
    const float* W2    = (const float*)d_in[9];
    const float* lamb  = (const float*)d_in[10];
    float* out = (float*)d_out;

    char* ws = (char*)d_ws;
    __hip_bfloat16* q_ws = (__hip_bfloat16*)ws;                       //  2 MB
    __hip_bfloat16* k_ws = (__hip_bfloat16*)(ws + (2u  << 20));       //  2 MB
    __hip_bfloat16* v_ws = (__hip_bfloat16*)(ws + (4u  << 20));       // 16 MB
    __hip_bfloat16* x_t  = (__hip_bfloat16*)(ws + (20u << 20));       // 16 MB
    float* sum_ws   = (float*)(ws + (36u << 20));
    float* sumsq_ws = sum_ws + Bb * Cc;
    float* coef     = sumsq_ws + Bb * Cc;
    __hip_bfloat16* w_bf = (__hip_bfloat16*)(ws + (37u << 20));       // 320 KB

    (void)hipFuncSetAttribute((const void*)attn_kernel,
                              hipFuncAttributeMaxDynamicSharedMemorySize, 114688);

    hipMemsetAsync(sum_ws, 0, 2 * Bb * Cc * sizeof(float), stream);
    wconv_kernel<<<5, 256, 0, stream>>>(Wq, Wk, Wv, w_bf);
    convt_kernel<<<dim3(Nn / 64, Cc / 64, Bb), 256, 0, stream>>>(x, x_t, sum_ws, sumsq_ws);
    proj_kernel<<<dim3(Nn / 64, 5, Bb), 256, 0, stream>>>(x_t, w_bf, bq, bk, bv, q_ws, k_ws, v_ws);
    gate_kernel<<<Bb, 256, 0, stream>>>(sum_ws, sumsq_ws, W1, W2, lamb, coef);
    attn_kernel<<<256, 512, 114688, stream>>>(q_ws, k_ws, v_ws, coef, x, gamma, out);
}